// Round 4
// baseline (531.915 us; speedup 1.0000x reference)
//
#include <hip/hip_runtime.h>
#include <math.h>

#define N1 50000
#define F_IN 128
#define E1 1000000
#define Bg 10
#define NPG 5000
#define N2 199
#define E2 4000
#define KSEL 50
#define LN_EPS 1e-5f
#define CHUNKS 16
#define CHSZ 313   // ceil(NPG/CHUNKS)
#define EBT 4096   // edges per bucket-pass block
#define NB 196     // ceil(N1/256) buckets of 256 dsts
#define BCAP 6144  // per-bucket capacity (mean ~5102, +14 sigma)

typedef unsigned long long ull;

// ---------------- phase B1: bin edges into 196 dst-buckets (+ graph2 CSR) ----------------
// payload: (dst & 255) << 16 | src   (src < 50000 < 2^16)
__global__ void k_bucket(const int* __restrict__ ei1, int* __restrict__ bcnt,
                         unsigned int* __restrict__ bed,
                         const int* __restrict__ ei2, int* __restrict__ rp2,
                         int* __restrict__ srcs2) {
  int t = threadIdx.x;  // 256
  int blk = blockIdx.x;
  const int nEdgeBlocks = (E1 + EBT - 1) / EBT;
  if (blk == nEdgeBlocks) {
    __shared__ int cnt2[N2];
    __shared__ int cur2[N2];
    const int* src = ei2;
    const int* dst = ei2 + E2;
    for (int i = t; i < N2; i += 256) cnt2[i] = 0;
    __syncthreads();
    for (int e = t; e < E2; e += 256) atomicAdd(&cnt2[dst[e]], 1);
    __syncthreads();
    if (t == 0) {
      int run = 0;
      rp2[0] = 0;
      for (int i = 0; i < N2; i++) {
        cur2[i] = run;
        run += cnt2[i];
        rp2[i + 1] = run;
      }
    }
    __syncthreads();
    for (int e = t; e < E2; e += 256) {
      int d = dst[e];
      int pos = atomicAdd(&cur2[d], 1);
      srcs2[pos] = src[e];
    }
    return;
  }
  __shared__ int hcnt[NB];
  const int* src = ei1;
  const int* dst = ei1 + E1;
  int e0 = blk * EBT;
  int e1 = min(e0 + EBT, E1);
  if (t < NB) hcnt[t] = 0;
  __syncthreads();
  for (int e = e0 + t; e < e1; e += 256) atomicAdd(&hcnt[dst[e] >> 8], 1);
  __syncthreads();
  if (t < NB) hcnt[t] = atomicAdd(&bcnt[t], hcnt[t]);
  __syncthreads();
  for (int e = e0 + t; e < e1; e += 256) {
    int d = dst[e];
    int s = src[e];
    int b = d >> 8;
    int pos = atomicAdd(&hcnt[b], 1);
    if (pos < BCAP)
      bed[(size_t)b * BCAP + pos] = ((unsigned int)(d & 255) << 16) | (unsigned int)s;
  }
}

// ---------------- phase B2: per-bucket CSR finalize (256 dsts per bucket) ----------------
__global__ __launch_bounds__(1024) void k_csr_bucket(
    const int* __restrict__ bcnt, const unsigned int* __restrict__ bed,
    int* __restrict__ rp, int* __restrict__ srcs) {
  __shared__ int cnt[256];
  __shared__ int cur[256];
  __shared__ int wsums[4];
  __shared__ int s_bbase;
  int b = blockIdx.x, t = threadIdx.x;
  int lane = t & 63, w = t >> 6;
  int total = min(bcnt[b], BCAP);
  if (t < 256) cnt[t] = 0;
  if (w == 0) {  // bucket base = sum of previous buckets' counts
    int vb = 0;
    for (int i = lane; i < b; i += 64) vb += min(bcnt[i], BCAP);
    for (int off = 32; off; off >>= 1) vb += __shfl_xor(vb, off);
    if (lane == 0) s_bbase = vb;
  }
  __syncthreads();
  const unsigned int* list = bed + (size_t)b * BCAP;
  for (int e = t; e < total; e += 1024) atomicAdd(&cnt[list[e] >> 16], 1);
  __syncthreads();
  int incl = 0, v = 0;
  if (t < 256) {
    v = cnt[t];
    int x = v;
#pragma unroll
    for (int off = 1; off < 64; off <<= 1) {
      int y = __shfl_up(x, off);
      if (lane >= off) x += y;
    }
    if (lane == 63) wsums[w] = x;
    incl = x;
  }
  __syncthreads();
  if (t < 256) {
    int pre = 0;
    for (int i = 0; i < w; i++) pre += wsums[i];
    incl += pre;
    int bbase = s_bbase;
    int node = b * 256 + t;
    if (node < N1) rp[node + 1] = bbase + incl;
    cur[t] = bbase + incl - v;
    if (b == 0 && t == 0) rp[0] = 0;
  }
  __syncthreads();
  for (int e = t; e < total; e += 1024) {
    unsigned int pe = list[e];
    int pos = atomicAdd(&cur[pe >> 16], 1);
    srcs[pos] = (int)(pe & 0xFFFFu);
  }
}

// ---------------- mean aggregation: 1 node/wave, float4/lane, 2 edges per wave-load ----------------
// srcs for the first 64 edges are loaded once (lane-indexed) and broadcast via shfl.
__global__ void k_aggr128(const float* __restrict__ xA, const int* __restrict__ rpA,
                          const int* __restrict__ srcsA, float* __restrict__ meanA, int nA,
                          const float* __restrict__ xB, const int* __restrict__ rpB,
                          const int* __restrict__ srcsB, float* __restrict__ meanB, int nB,
                          int blocksA) {
  int blk = blockIdx.x;
  const float* x;
  const int* rp;
  const int* srcs;
  float* mean;
  int n, nb0;
  if (blk < blocksA) { x = xA; rp = rpA; srcs = srcsA; mean = meanA; n = nA; nb0 = blk * 4; }
  else { x = xB; rp = rpB; srcs = srcsB; mean = meanB; n = nB; nb0 = (blk - blocksA) * 4; }
  int lane = threadIdx.x & 63;
  int node = nb0 + (threadIdx.x >> 6);
  if (node >= n) return;
  int s = rp[node], e = rp[node + 1];
  int deg = e - s;
  int half = lane >> 5;
  int sub = lane & 31;
  const float4* xp = (const float4*)x;
  float4 acc = make_float4(0.f, 0.f, 0.f, 0.f);
  int sv = 0;
  if (s + lane < e) sv = srcs[s + lane];
  int lim = deg < 64 ? deg : 64;
  int i = 0;
  for (; i + 8 <= lim; i += 8) {
    int s0 = __shfl(sv, i + half);
    int s1 = __shfl(sv, i + 2 + half);
    int s2 = __shfl(sv, i + 4 + half);
    int s3 = __shfl(sv, i + 6 + half);
    float4 v0 = xp[(size_t)s0 * 32 + sub];
    float4 v1 = xp[(size_t)s1 * 32 + sub];
    float4 v2 = xp[(size_t)s2 * 32 + sub];
    float4 v3 = xp[(size_t)s3 * 32 + sub];
    acc.x += (v0.x + v1.x) + (v2.x + v3.x);
    acc.y += (v0.y + v1.y) + (v2.y + v3.y);
    acc.z += (v0.z + v1.z) + (v2.z + v3.z);
    acc.w += (v0.w + v1.w) + (v2.w + v3.w);
  }
  for (; i + 2 <= lim; i += 2) {
    int s0 = __shfl(sv, i + half);
    float4 v = xp[(size_t)s0 * 32 + sub];
    acc.x += v.x; acc.y += v.y; acc.z += v.z; acc.w += v.w;
  }
  if (i < lim) {
    int s0 = __shfl(sv, i);
    if (half == 0) {
      float4 v = xp[(size_t)s0 * 32 + sub];
      acc.x += v.x; acc.y += v.y; acc.z += v.z; acc.w += v.w;
    }
    i = lim;
  }
  // rare tail: degree > 64, continue with direct srcs loads (same grouping as before)
  if (deg > 64) {
    int ii = s + 64;
    for (; ii + 8 <= e; ii += 8) {
      int s0 = srcs[ii + half];
      int s1 = srcs[ii + 2 + half];
      int s2 = srcs[ii + 4 + half];
      int s3 = srcs[ii + 6 + half];
      float4 v0 = xp[(size_t)s0 * 32 + sub];
      float4 v1 = xp[(size_t)s1 * 32 + sub];
      float4 v2 = xp[(size_t)s2 * 32 + sub];
      float4 v3 = xp[(size_t)s3 * 32 + sub];
      acc.x += (v0.x + v1.x) + (v2.x + v3.x);
      acc.y += (v0.y + v1.y) + (v2.y + v3.y);
      acc.z += (v0.z + v1.z) + (v2.z + v3.z);
      acc.w += (v0.w + v1.w) + (v2.w + v3.w);
    }
    for (; ii + 2 <= e; ii += 2) {
      int s0 = srcs[ii + half];
      float4 v = xp[(size_t)s0 * 32 + sub];
      acc.x += v.x; acc.y += v.y; acc.z += v.z; acc.w += v.w;
    }
    if (ii < e && half == 0) {
      float4 v = xp[(size_t)srcs[ii] * 32 + sub];
      acc.x += v.x; acc.y += v.y; acc.z += v.z; acc.w += v.w;
    }
  }
  acc.x += __shfl_xor(acc.x, 32);
  acc.y += __shfl_xor(acc.y, 32);
  acc.z += __shfl_xor(acc.z, 32);
  acc.w += __shfl_xor(acc.w, 32);
  if (half == 0) {
    float c = (float)(deg > 0 ? deg : 1);
    float inv = 1.f / c;
    float4 o = make_float4(acc.x * inv, acc.y * inv, acc.z * inv, acc.w * inv);
    ((float4*)mean)[(size_t)node * 32 + sub] = o;
  }
}

// ---------------- fused layer-2 aggregate: float4/lane, 4 edges per wave-load ----------------
__global__ void k_aggr_fused64(const float* __restrict__ zA, const int* __restrict__ rpA,
                               const int* __restrict__ srcsA, float* __restrict__ outA, int nA,
                               const float* __restrict__ zB, const int* __restrict__ rpB,
                               const int* __restrict__ srcsB, float* __restrict__ outB, int nB,
                               const float* __restrict__ bias, int blocksA) {
  int blk = blockIdx.x;
  const float* zlr;
  const int* rp;
  const int* srcs;
  float* out;
  int n, nb0;
  if (blk < blocksA) { zlr = zA; rp = rpA; srcs = srcsA; out = outA; n = nA; nb0 = blk * 4; }
  else { zlr = zB; rp = rpB; srcs = srcsB; out = outB; n = nB; nb0 = (blk - blocksA) * 4; }
  int lane = threadIdx.x & 63;
  int node = nb0 + (threadIdx.x >> 6);
  if (node >= n) return;
  int s = rp[node], e = rp[node + 1];
  int deg = e - s;
  int q = lane >> 4;
  int sub = lane & 15;
  const float4* zp = (const float4*)zlr;
  float4 acc = make_float4(0.f, 0.f, 0.f, 0.f);
  int sv = 0;
  if (s + lane < e) sv = srcs[s + lane];
  int lim = deg < 64 ? deg : 64;
  int i = 0;
  for (; i + 8 <= lim; i += 8) {
    int s0 = __shfl(sv, i + q);
    int s1 = __shfl(sv, i + 4 + q);
    float4 v0 = zp[(size_t)s0 * 32 + sub];
    float4 v1 = zp[(size_t)s1 * 32 + sub];
    acc.x += v0.x + v1.x;
    acc.y += v0.y + v1.y;
    acc.z += v0.z + v1.z;
    acc.w += v0.w + v1.w;
  }
  for (; i + 4 <= lim; i += 4) {
    int s0 = __shfl(sv, i + q);
    float4 v = zp[(size_t)s0 * 32 + sub];
    acc.x += v.x; acc.y += v.y; acc.z += v.z; acc.w += v.w;
  }
  {
    int rem = lim - i;
    int s0 = __shfl(sv, i + q);
    if (q < rem) {
      float4 v = zp[(size_t)s0 * 32 + sub];
      acc.x += v.x; acc.y += v.y; acc.z += v.z; acc.w += v.w;
    }
    i = lim;
  }
  if (deg > 64) {  // rare tail, direct loads, same grouping
    int ii = s + 64;
    for (; ii + 8 <= e; ii += 8) {
      int s0 = srcs[ii + q];
      int s1 = srcs[ii + 4 + q];
      float4 v0 = zp[(size_t)s0 * 32 + sub];
      float4 v1 = zp[(size_t)s1 * 32 + sub];
      acc.x += v0.x + v1.x;
      acc.y += v0.y + v1.y;
      acc.z += v0.z + v1.z;
      acc.w += v0.w + v1.w;
    }
    for (; ii + 4 <= e; ii += 4) {
      int s0 = srcs[ii + q];
      float4 v = zp[(size_t)s0 * 32 + sub];
      acc.x += v.x; acc.y += v.y; acc.z += v.z; acc.w += v.w;
    }
    int rem = e - ii;
    if (q < rem) {
      int s0 = srcs[ii + q];
      float4 v = zp[(size_t)s0 * 32 + sub];
      acc.x += v.x; acc.y += v.y; acc.z += v.z; acc.w += v.w;
    }
  }
  acc.x += __shfl_xor(acc.x, 16);
  acc.y += __shfl_xor(acc.y, 16);
  acc.z += __shfl_xor(acc.z, 16);
  acc.w += __shfl_xor(acc.w, 16);
  acc.x += __shfl_xor(acc.x, 32);
  acc.y += __shfl_xor(acc.y, 32);
  acc.z += __shfl_xor(acc.z, 32);
  acc.w += __shfl_xor(acc.w, 32);
  if (q == 0) {
    float c = (float)(deg > 0 ? deg : 1);
    float inv = 1.f / c;
    float4 mb = ((const float4*)bias)[sub];
    float4 rt = zp[(size_t)node * 32 + 16 + sub];
    float v0 = acc.x * inv + mb.x + rt.x;
    float v1 = acc.y * inv + mb.y + rt.y;
    float v2 = acc.z * inv + mb.z + rt.z;
    float v3 = acc.w * inv + mb.w + rt.w;
    float4 o;
    o.x = v0 > 0.f ? v0 : 0.f;
    o.y = v1 > 0.f ? v1 : 0.f;
    o.z = v2 > 0.f ? v2 : 0.f;
    o.w = v3 > 0.f ? v3 : 0.f;
    ((float4*)out)[(size_t)node * 16 + sub] = o;
  }
}

// ---------------- fused SAGE layer-1 GEMM + layer-2 dual linear ----------------
// GEMM1: h = relu(mean@w1l^T + b1l + x@w1r^T)   (h kept in registers, 8x8/thread)
// GEMM2: z = [h@w2l^T | h@w2r^T]                (h transposed into s_a per 32-K chunk)
// v4: W is read DIRECTLY from global (L1/L2-resident, 16 lanes share each address)
// instead of via LDS: round-3 arithmetic showed the kernel is LDS-read-pipe-bound
// (ds_read_b128 ~12cyc; v2 ~65% / v3 ~84% LDS-busy vs VALU need 36us). Moving the
// W stream (half of all LDS reads) to the idle VMEM/L1 pipe + dropping s_w staging
// rebalances LDS:VALU from ~1.7:1 to ~0.6:1. TM back to 128 (v3's TM=64 regressed).
// Chunk order, kk order and FMA order unchanged -> bitwise-identical output.
__global__ __launch_bounds__(256) void k_sage_lin(
    const float* __restrict__ xinA, const float* __restrict__ meanA,
    float* __restrict__ zA, int nA,
    const float* __restrict__ xinB, const float* __restrict__ meanB,
    float* __restrict__ zB, int nB,
    const float* __restrict__ w1l, const float* __restrict__ b1l,
    const float* __restrict__ w1r,
    const float* __restrict__ w2l, const float* __restrict__ w2r, int blocksA) {
  constexpr int TM = 128, TK = 32;
  constexpr int SA = TM + 4;
  __shared__ float s_a[TK][SA];
  int blk = blockIdx.x;
  const float* xin;
  const float* mean;
  float* zlr;
  int n, m0;
  if (blk < blocksA) { xin = xinA; mean = meanA; zlr = zA; n = nA; m0 = blk * TM; }
  else { xin = xinB; mean = meanB; zlr = zB; n = nB; m0 = (blk - blocksA) * TM; }
  int t = threadIdx.x;
  int tx = t & 15, ty = t >> 4;
  int sub = t >> 3;
  int kv = (t & 7) << 2;

  // per-thread W row bases (rows tx*8..tx*8+7 of each weight matrix)
  const float* wbL1 = w1l + (size_t)(tx * 8) * 128;
  const float* wbR1 = w1r + (size_t)(tx * 8) * 128;
  const float* wb2 = (tx < 8) ? (w2l + (size_t)(tx * 8) * 128)
                              : (w2r + (size_t)((tx - 8) * 8) * 128);

  float acc[8][8];
#pragma unroll
  for (int i = 0; i < 8; i++)
#pragma unroll
    for (int j = 0; j < 8; j++) acc[i][j] = 0.f;
  float h[8][8];
  float4 ra[4];

  // prologue: prefetch chunk 0 A-tile (mean, k0 = 0)
#pragma unroll
  for (int p = 0; p < 4; p++) {
    int node = m0 + p * 32 + sub;
    ra[p] = make_float4(0.f, 0.f, 0.f, 0.f);
    if (node < n) ra[p] = *(const float4*)&mean[(size_t)node * 128 + kv];
  }

  for (int c = 0; c < 12; c++) {
    __syncthreads();  // previous chunk's LDS reads complete
    if (c < 8) {
#pragma unroll
      for (int p = 0; p < 4; p++) {
        int col = p * 32 + sub;
        s_a[kv + 0][col] = ra[p].x;
        s_a[kv + 1][col] = ra[p].y;
        s_a[kv + 2][col] = ra[p].z;
        s_a[kv + 3][col] = ra[p].w;
      }
    } else {
      // h transpose: this thread's h cols tx*8+j lie in [k0,k0+32) iff txk in [0,4)
      int txk = tx - (c - 8) * 4;
      if (txk >= 0 && txk < 4) {
#pragma unroll
        for (int i = 0; i < 8; i++)
#pragma unroll
          for (int j = 0; j < 8; j++) s_a[txk * 8 + j][ty * 8 + i] = h[i][j];
      }
    }
    // prefetch next chunk's A-tile; latency hides under this chunk's compute
    int cn = c + 1;
    if (cn < 8) {
      const float* A = (cn < 4) ? mean : xin;
      int k0n = (cn & 3) * 32;
#pragma unroll
      for (int p = 0; p < 4; p++) {
        int node = m0 + p * 32 + sub;
        ra[p] = make_float4(0.f, 0.f, 0.f, 0.f);
        if (node < n) ra[p] = *(const float4*)&A[(size_t)node * 128 + k0n + kv];
      }
    }
    __syncthreads();
    const float* wb = (c < 4) ? wbL1 : (c < 8) ? wbR1 : wb2;
    int k0 = (c & 3) * 32;
#pragma unroll
    for (int kk4 = 0; kk4 < 8; kk4++) {
      float4 wf[8];
#pragma unroll
      for (int jj = 0; jj < 8; jj++)
        wf[jj] = *(const float4*)&wb[jj * 128 + k0 + kk4 * 4];
      const float* wfp = (const float*)wf;
#pragma unroll
      for (int dk = 0; dk < 4; dk++) {
        int kk = kk4 * 4 + dk;
        float4 a0 = *(const float4*)&s_a[kk][ty * 8];
        float4 a1 = *(const float4*)&s_a[kk][ty * 8 + 4];
        float av[8] = {a0.x, a0.y, a0.z, a0.w, a1.x, a1.y, a1.z, a1.w};
#pragma unroll
        for (int i = 0; i < 8; i++)
#pragma unroll
          for (int jj = 0; jj < 8; jj++)
            acc[i][jj] = fmaf(av[i], wfp[jj * 4 + dk], acc[i][jj]);
      }
    }
    if (c == 7) {
      // GEMM1 done: bias + relu -> h in registers; reset acc for GEMM2
      float bj[8];
#pragma unroll
      for (int j = 0; j < 8; j++) bj[j] = b1l[tx * 8 + j];
#pragma unroll
      for (int i = 0; i < 8; i++)
#pragma unroll
        for (int j = 0; j < 8; j++) {
          float v = acc[i][j] + bj[j];
          h[i][j] = v > 0.f ? v : 0.f;
          acc[i][j] = 0.f;
        }
    }
  }
  // ---- epilogue: write z (no bias/relu) ----
#pragma unroll
  for (int i = 0; i < 8; i++) {
    int node = m0 + ty * 8 + i;
    if (node < n) {
#pragma unroll
      for (int q = 0; q < 8; q += 4) {
        float4 o = make_float4(acc[i][q + 0], acc[i][q + 1], acc[i][q + 2], acc[i][q + 3]);
        *(float4*)&zlr[(size_t)node * 128 + tx * 8 + q] = o;
      }
    }
  }
}

// ---------------- fused score + per-chunk bitonic top-50 (16 chunks of 313) ----------------
__global__ void k_score_topk_local(const float* __restrict__ out1,
                                   const float* __restrict__ out2,
                                   ull* __restrict__ cand) {
  __shared__ ull s[512];
  __shared__ float brow[64];
  int blk = blockIdx.x;  // 0..159
  int b = blk >> 4, c = blk & 15;
  int t = threadIdx.x;   // 256
  if (t < 64) brow[t] = out2[198 * 64 + t];
  __syncthreads();
  const float4* b4 = (const float4*)brow;
  float b2 = 0.f;
#pragma unroll
  for (int q = 0; q < 16; q++) {
    float4 w = b4[q];
    b2 = fmaf(w.x, w.x, fmaf(w.y, w.y, fmaf(w.z, w.z, fmaf(w.w, w.w, b2))));
  }
#pragma unroll
  for (int p = 0; p < 2; p++) {
    int i = p * 256 + t;
    ull key = 0ULL;
    int gidx = c * CHSZ + i;
    if (i < CHSZ && gidx < NPG) {
      const float4* ap = (const float4*)&out1[((size_t)b * NPG + gidx) * 64];
      float dot = 0.f, a2 = 0.f;
#pragma unroll
      for (int q = 0; q < 16; q++) {
        float4 a = ap[q];
        float4 w = b4[q];
        dot = fmaf(a.x, w.x, fmaf(a.y, w.y, fmaf(a.z, w.z, fmaf(a.w, w.w, dot))));
        a2 = fmaf(a.x, a.x, fmaf(a.y, a.y, fmaf(a.z, a.z, fmaf(a.w, a.w, a2))));
      }
      float d2 = a2 + b2 - 2.f * dot;
      float sc = sqrtf(fmaxf(d2, 0.f));
      key = ((ull)__float_as_uint(sc) << 32) | (unsigned int)(~gidx);
    }
    s[i] = key;
  }
  __syncthreads();
  for (int k = 2; k <= 512; k <<= 1) {
    for (int j = k >> 1; j > 0; j >>= 1) {
#pragma unroll
      for (int p = 0; p < 2; p++) {
        int i = p * 256 + t;
        int l = i ^ j;
        if (l > i) {
          bool up = ((i & k) != 0);
          ull a = s[i], bb = s[l];
          if ((a > bb) == up) { s[i] = bb; s[l] = a; }
        }
      }
      __syncthreads();
    }
  }
  if (t < KSEL) cand[(b * CHUNKS + c) * KSEL + t] = s[t];
}

// ---------------- top-50 merge: sort 800 candidates (pad 1024), emit sel ----------------
__global__ void k_topk_merge(const ull* __restrict__ cand, int* __restrict__ sel) {
  __shared__ ull s[1024];
  int b = blockIdx.x, t = threadIdx.x;  // 256
#pragma unroll
  for (int p = 0; p < 4; p++) {
    int i = p * 256 + t;
    s[i] = (i < CHUNKS * KSEL) ? cand[b * CHUNKS * KSEL + i] : 0ULL;
  }
  __syncthreads();
  for (int k = 2; k <= 1024; k <<= 1) {
    for (int j = k >> 1; j > 0; j >>= 1) {
#pragma unroll
      for (int p = 0; p < 4; p++) {
        int i = p * 256 + t;
        int l = i ^ j;
        if (l > i) {
          bool up = ((i & k) != 0);
          ull a = s[i], bb = s[l];
          if ((a > bb) == up) { s[i] = bb; s[l] = a; }
        }
      }
      __syncthreads();
    }
  }
  if (t < KSEL) {
    int gidx = (int)(~((unsigned int)s[t]));
    sel[b * KSEL + t] = b * NPG + gidx;
  }
}

// ---------------- dist rows for selected nodes: D[500][199] ----------------
__global__ void k_dist_rows(const float* __restrict__ out1, const float* __restrict__ out2,
                            const int* __restrict__ sel, float* __restrict__ D) {
  __shared__ float arow[64];
  int i = blockIdx.x;   // 0..499
  int t = threadIdx.x;  // 256
  int node = sel[i];
  if (t < 64) arow[t] = out1[(size_t)node * 64 + t];
  __syncthreads();
  float a2 = 0.f;
#pragma unroll
  for (int f = 0; f < 64; f++) a2 = fmaf(arow[f], arow[f], a2);
  for (int nn = t; nn < N2; nn += 256) {
    float dot = 0.f, b2 = 0.f;
#pragma unroll 8
    for (int f = 0; f < 64; f++) {
      float bv = out2[nn * 64 + f];
      dot = fmaf(arow[f], bv, dot);
      b2 = fmaf(bv, bv, b2);
    }
    float d2 = a2 + b2 - 2.f * dot;
    D[i * N2 + nn] = sqrtf(fmaxf(d2, 0.f));
  }
}

// ---------------- fc1 dot: one block per output feature j, all 10 graphs ----------------
__global__ void k_fc1_dot(const float* __restrict__ D, const float* __restrict__ w,
                          float* __restrict__ h1pre) {
  constexpr int M = KSEL * N2;  // 9950
  constexpr int M2 = M / 2;     // 4975
  int j = blockIdx.x;           // 0..127
  int t = threadIdx.x;          // 256
  const float2* wp = (const float2*)(w + (size_t)j * M);
  float acc[Bg];
#pragma unroll
  for (int b = 0; b < Bg; b++) acc[b] = 0.f;
  for (int m = t; m < M2; m += 256) {
    float2 wv = wp[m];
#pragma unroll
    for (int b = 0; b < Bg; b++) {
      float2 dv = ((const float2*)(D + (size_t)b * M))[m];
      acc[b] = fmaf(dv.x, wv.x, fmaf(dv.y, wv.y, acc[b]));
    }
  }
  __shared__ float ws_[4][Bg];
  int lane = t & 63, wv_ = t >> 6;
#pragma unroll
  for (int b = 0; b < Bg; b++) {
    float v = acc[b];
    for (int off = 32; off; off >>= 1) v += __shfl_xor(v, off);
    if (lane == 0) ws_[wv_][b] = v;
  }
  __syncthreads();
  if (t < Bg) h1pre[t * 128 + j] = ws_[0][t] + ws_[1][t] + ws_[2][t] + ws_[3][t];
}

// ---------------- fused: fc1 bias+LN+relu, fc2+LN+relu, fc3+sigmoid ----------------
__global__ void k_fc123(const float* __restrict__ h1pre, const float* __restrict__ fc1b,
                        const float* __restrict__ g1, const float* __restrict__ be1,
                        const float* __restrict__ w2, const float* __restrict__ b2v,
                        const float* __restrict__ g2, const float* __restrict__ be2,
                        const float* __restrict__ w3, const float* __restrict__ b3,
                        float* __restrict__ out) {
  __shared__ float wsum[2];
  __shared__ float sh[128];
  int b = blockIdx.x, t = threadIdx.x;  // 128
  float acc = h1pre[b * 128 + t] + fc1b[t];
  int lane = t & 63, wv_ = t >> 6;
  float ssum = acc;
  for (int off = 32; off; off >>= 1) ssum += __shfl_xor(ssum, off);
  if (lane == 0) wsum[wv_] = ssum;
  __syncthreads();
  float mu = (wsum[0] + wsum[1]) / 128.f;
  __syncthreads();
  float d = acc - mu;
  float vv = d * d;
  for (int off = 32; off; off >>= 1) vv += __shfl_xor(vv, off);
  if (lane == 0) wsum[wv_] = vv;
  __syncthreads();
  float var = (wsum[0] + wsum[1]) / 128.f;
  float r = rsqrtf(var + LN_EPS);
  float h = d * r * g1[t] + be1[t];
  sh[t] = h > 0.f ? h : 0.f;
  __syncthreads();
  if (t < 64) {
    float a2 = b2v[t];
#pragma unroll 8
    for (int k = 0; k < 128; k++) a2 = fmaf(sh[k], w2[t * 128 + k], a2);
    float s2 = a2;
    for (int off = 32; off; off >>= 1) s2 += __shfl_xor(s2, off);
    float mu2 = s2 * (1.f / 64.f);
    float d2 = a2 - mu2;
    float vv2 = d2 * d2;
    for (int off = 32; off; off >>= 1) vv2 += __shfl_xor(vv2, off);
    float r2 = rsqrtf(vv2 * (1.f / 64.f) + LN_EPS);
    float h2 = d2 * r2 * g2[t] + be2[t];
    h2 = h2 > 0.f ? h2 : 0.f;
    float pp = h2 * w3[t];
    for (int off = 32; off; off >>= 1) pp += __shfl_xor(pp, off);
    if (t == 0) out[b] = 1.f / (1.f + expf(-(pp + b3[0])));
  }
}

extern "C" void kernel_launch(void* const* d_in, const int* in_sizes, int n_in,
                              void* d_out, int out_size, void* d_ws, size_t ws_size,
                              hipStream_t stream) {
  const float* x1 = (const float*)d_in[0];
  const int* ei1 = (const int*)d_in[1];
  const float* x2 = (const float*)d_in[3];
  const int* ei2 = (const int*)d_in[4];
  const float* w1l = (const float*)d_in[5];
  const float* b1l = (const float*)d_in[6];
  const float* w1r = (const float*)d_in[7];
  const float* w2l = (const float*)d_in[8];
  const float* b2l = (const float*)d_in[9];
  const float* w2r = (const float*)d_in[10];
  const float* fc1w = (const float*)d_in[11];
  const float* fc1b = (const float*)d_in[12];
  const float* ln1g = (const float*)d_in[13];
  const float* ln1b = (const float*)d_in[14];
  const float* fc2w = (const float*)d_in[15];
  const float* fc2b = (const float*)d_in[16];
  const float* ln2g = (const float*)d_in[17];
  const float* ln2b = (const float*)d_in[18];
  const float* fc3w = (const float*)d_in[19];
  const float* fc3b = (const float*)d_in[20];
  float* out = (float*)d_out;

  char* p = (char*)d_ws;
  auto alloc = [&](size_t bytes) {
    char* r = p;
    p += (bytes + 255) & ~(size_t)255;
    return r;
  };
  int* rp1 = (int*)alloc((N1 + 1) * 4);
  int* bcnt = (int*)alloc(NB * 4);
  unsigned int* bed = (unsigned int*)alloc((size_t)NB * BCAP * 4);
  int* srcs1 = (int*)alloc((size_t)E1 * 4);
  int* rp2 = (int*)alloc((N2 + 1) * 4);
  int* srcs2 = (int*)alloc(E2 * 4);
  float* bufMean = (float*)alloc((size_t)N1 * 128 * 4);  // mean agg (layer 1)
  float* bufZ = (float*)alloc((size_t)N1 * 128 * 4);     // zlr = [h@w2l^T | h@w2r^T]
  float* out1b = (float*)alloc((size_t)N1 * 64 * 4);
  float* mean2 = (float*)alloc((size_t)N2 * 128 * 4);
  float* z2g = (float*)alloc((size_t)N2 * 128 * 4);
  float* out2b = (float*)alloc((size_t)N2 * 64 * 4);
  int* sel = (int*)alloc(Bg * KSEL * 4);
  ull* cand = (ull*)alloc((size_t)Bg * CHUNKS * KSEL * 8);
  float* Dm = (float*)alloc((size_t)Bg * KSEL * N2 * 4);
  float* h1pre = (float*)alloc(Bg * 128 * 4);

  const int nEdgeBlocks = (E1 + EBT - 1) / EBT;
  const int aggrBlocksA = (N1 + 3) / 4;
  const int aggrBlocksB = (N2 + 3) / 4;
  const int gemmBlocksA = (N1 + 127) / 128;
  const int gemmBlocksB = (N2 + 127) / 128;

  // ---- CSR build ----
  hipMemsetAsync(bcnt, 0, NB * 4, stream);
  k_bucket<<<nEdgeBlocks + 1, 256, 0, stream>>>(ei1, bcnt, bed, ei2, rp2, srcs2);
  k_csr_bucket<<<NB, 1024, 0, stream>>>(bcnt, bed, rp1, srcs1);
  // ---- GNN (both graphs per launch) ----
  k_aggr128<<<aggrBlocksA + aggrBlocksB, 256, 0, stream>>>(
      x1, rp1, srcs1, bufMean, N1, x2, rp2, srcs2, mean2, N2, aggrBlocksA);
  k_sage_lin<<<gemmBlocksA + gemmBlocksB, 256, 0, stream>>>(
      x1, bufMean, bufZ, N1, x2, mean2, z2g, N2, w1l, b1l, w1r, w2l, w2r, gemmBlocksA);
  k_aggr_fused64<<<aggrBlocksA + aggrBlocksB, 256, 0, stream>>>(
      bufZ, rp1, srcs1, out1b, N1, z2g, rp2, srcs2, out2b, N2, b2l, aggrBlocksA);
  // ---- head ----
  k_score_topk_local<<<Bg * CHUNKS, 256, 0, stream>>>(out1b, out2b, cand);
  k_topk_merge<<<Bg, 256, 0, stream>>>(cand, sel);
  k_dist_rows<<<Bg * KSEL, 256, 0, stream>>>(out1b, out2b, sel, Dm);
  k_fc1_dot<<<128, 256, 0, stream>>>(Dm, fc1w, h1pre);
  k_fc123<<<Bg, 128, 0, stream>>>(h1pre, fc1b, ln1g, ln1b, fc2w, fc2b, ln2g, ln2b,
                                  fc3w, fc3b, out);
}

// Round 5
// 383.332 us; speedup vs baseline: 1.3876x; 1.3876x over previous
//
#include <hip/hip_runtime.h>
#include <math.h>

#define N1 50000
#define F_IN 128
#define E1 1000000
#define Bg 10
#define NPG 5000
#define N2 199
#define E2 4000
#define KSEL 50
#define LN_EPS 1e-5f
#define CHUNKS 16
#define CHSZ 313   // ceil(NPG/CHUNKS)
#define EBT 4096   // edges per bucket-pass block
#define NB 196     // ceil(N1/256) buckets of 256 dsts
#define BCAP 6144  // per-bucket capacity (mean ~5102, +14 sigma)

typedef unsigned long long ull;

// ---------------- phase B1: bin edges into 196 dst-buckets (+ graph2 CSR) ----------------
// payload: (dst & 255) << 16 | src   (src < 50000 < 2^16)
__global__ void k_bucket(const int* __restrict__ ei1, int* __restrict__ bcnt,
                         unsigned int* __restrict__ bed,
                         const int* __restrict__ ei2, int* __restrict__ rp2,
                         int* __restrict__ srcs2) {
  int t = threadIdx.x;  // 256
  int blk = blockIdx.x;
  const int nEdgeBlocks = (E1 + EBT - 1) / EBT;
  if (blk == nEdgeBlocks) {
    __shared__ int cnt2[N2];
    __shared__ int cur2[N2];
    const int* src = ei2;
    const int* dst = ei2 + E2;
    for (int i = t; i < N2; i += 256) cnt2[i] = 0;
    __syncthreads();
    for (int e = t; e < E2; e += 256) atomicAdd(&cnt2[dst[e]], 1);
    __syncthreads();
    if (t == 0) {
      int run = 0;
      rp2[0] = 0;
      for (int i = 0; i < N2; i++) {
        cur2[i] = run;
        run += cnt2[i];
        rp2[i + 1] = run;
      }
    }
    __syncthreads();
    for (int e = t; e < E2; e += 256) {
      int d = dst[e];
      int pos = atomicAdd(&cur2[d], 1);
      srcs2[pos] = src[e];
    }
    return;
  }
  __shared__ int hcnt[NB];
  const int* src = ei1;
  const int* dst = ei1 + E1;
  int e0 = blk * EBT;
  int e1 = min(e0 + EBT, E1);
  if (t < NB) hcnt[t] = 0;
  __syncthreads();
  for (int e = e0 + t; e < e1; e += 256) atomicAdd(&hcnt[dst[e] >> 8], 1);
  __syncthreads();
  if (t < NB) hcnt[t] = atomicAdd(&bcnt[t], hcnt[t]);
  __syncthreads();
  for (int e = e0 + t; e < e1; e += 256) {
    int d = dst[e];
    int s = src[e];
    int b = d >> 8;
    int pos = atomicAdd(&hcnt[b], 1);
    if (pos < BCAP)
      bed[(size_t)b * BCAP + pos] = ((unsigned int)(d & 255) << 16) | (unsigned int)s;
  }
}

// ---------------- phase B2: per-bucket CSR finalize (256 dsts per bucket) ----------------
__global__ __launch_bounds__(1024) void k_csr_bucket(
    const int* __restrict__ bcnt, const unsigned int* __restrict__ bed,
    int* __restrict__ rp, int* __restrict__ srcs) {
  __shared__ int cnt[256];
  __shared__ int cur[256];
  __shared__ int wsums[4];
  __shared__ int s_bbase;
  int b = blockIdx.x, t = threadIdx.x;
  int lane = t & 63, w = t >> 6;
  int total = min(bcnt[b], BCAP);
  if (t < 256) cnt[t] = 0;
  if (w == 0) {  // bucket base = sum of previous buckets' counts
    int vb = 0;
    for (int i = lane; i < b; i += 64) vb += min(bcnt[i], BCAP);
    for (int off = 32; off; off >>= 1) vb += __shfl_xor(vb, off);
    if (lane == 0) s_bbase = vb;
  }
  __syncthreads();
  const unsigned int* list = bed + (size_t)b * BCAP;
  for (int e = t; e < total; e += 1024) atomicAdd(&cnt[list[e] >> 16], 1);
  __syncthreads();
  int incl = 0, v = 0;
  if (t < 256) {
    v = cnt[t];
    int x = v;
#pragma unroll
    for (int off = 1; off < 64; off <<= 1) {
      int y = __shfl_up(x, off);
      if (lane >= off) x += y;
    }
    if (lane == 63) wsums[w] = x;
    incl = x;
  }
  __syncthreads();
  if (t < 256) {
    int pre = 0;
    for (int i = 0; i < w; i++) pre += wsums[i];
    incl += pre;
    int bbase = s_bbase;
    int node = b * 256 + t;
    if (node < N1) rp[node + 1] = bbase + incl;
    cur[t] = bbase + incl - v;
    if (b == 0 && t == 0) rp[0] = 0;
  }
  __syncthreads();
  for (int e = t; e < total; e += 1024) {
    unsigned int pe = list[e];
    int pos = atomicAdd(&cur[pe >> 16], 1);
    srcs[pos] = (int)(pe & 0xFFFFu);
  }
}

// ---------------- mean aggregation: 1 node/wave, float4/lane, 2 edges per wave-load ----------------
// srcs for the first 64 edges are loaded once (lane-indexed) and broadcast via shfl.
__global__ void k_aggr128(const float* __restrict__ xA, const int* __restrict__ rpA,
                          const int* __restrict__ srcsA, float* __restrict__ meanA, int nA,
                          const float* __restrict__ xB, const int* __restrict__ rpB,
                          const int* __restrict__ srcsB, float* __restrict__ meanB, int nB,
                          int blocksA) {
  int blk = blockIdx.x;
  const float* x;
  const int* rp;
  const int* srcs;
  float* mean;
  int n, nb0;
  if (blk < blocksA) { x = xA; rp = rpA; srcs = srcsA; mean = meanA; n = nA; nb0 = blk * 4; }
  else { x = xB; rp = rpB; srcs = srcsB; mean = meanB; n = nB; nb0 = (blk - blocksA) * 4; }
  int lane = threadIdx.x & 63;
  int node = nb0 + (threadIdx.x >> 6);
  if (node >= n) return;
  int s = rp[node], e = rp[node + 1];
  int deg = e - s;
  int half = lane >> 5;
  int sub = lane & 31;
  const float4* xp = (const float4*)x;
  float4 acc = make_float4(0.f, 0.f, 0.f, 0.f);
  int sv = 0;
  if (s + lane < e) sv = srcs[s + lane];
  int lim = deg < 64 ? deg : 64;
  int i = 0;
  for (; i + 8 <= lim; i += 8) {
    int s0 = __shfl(sv, i + half);
    int s1 = __shfl(sv, i + 2 + half);
    int s2 = __shfl(sv, i + 4 + half);
    int s3 = __shfl(sv, i + 6 + half);
    float4 v0 = xp[(size_t)s0 * 32 + sub];
    float4 v1 = xp[(size_t)s1 * 32 + sub];
    float4 v2 = xp[(size_t)s2 * 32 + sub];
    float4 v3 = xp[(size_t)s3 * 32 + sub];
    acc.x += (v0.x + v1.x) + (v2.x + v3.x);
    acc.y += (v0.y + v1.y) + (v2.y + v3.y);
    acc.z += (v0.z + v1.z) + (v2.z + v3.z);
    acc.w += (v0.w + v1.w) + (v2.w + v3.w);
  }
  for (; i + 2 <= lim; i += 2) {
    int s0 = __shfl(sv, i + half);
    float4 v = xp[(size_t)s0 * 32 + sub];
    acc.x += v.x; acc.y += v.y; acc.z += v.z; acc.w += v.w;
  }
  if (i < lim) {
    int s0 = __shfl(sv, i);
    if (half == 0) {
      float4 v = xp[(size_t)s0 * 32 + sub];
      acc.x += v.x; acc.y += v.y; acc.z += v.z; acc.w += v.w;
    }
    i = lim;
  }
  // rare tail: degree > 64, continue with direct srcs loads (same grouping as before)
  if (deg > 64) {
    int ii = s + 64;
    for (; ii + 8 <= e; ii += 8) {
      int s0 = srcs[ii + half];
      int s1 = srcs[ii + 2 + half];
      int s2 = srcs[ii + 4 + half];
      int s3 = srcs[ii + 6 + half];
      float4 v0 = xp[(size_t)s0 * 32 + sub];
      float4 v1 = xp[(size_t)s1 * 32 + sub];
      float4 v2 = xp[(size_t)s2 * 32 + sub];
      float4 v3 = xp[(size_t)s3 * 32 + sub];
      acc.x += (v0.x + v1.x) + (v2.x + v3.x);
      acc.y += (v0.y + v1.y) + (v2.y + v3.y);
      acc.z += (v0.z + v1.z) + (v2.z + v3.z);
      acc.w += (v0.w + v1.w) + (v2.w + v3.w);
    }
    for (; ii + 2 <= e; ii += 2) {
      int s0 = srcs[ii + half];
      float4 v = xp[(size_t)s0 * 32 + sub];
      acc.x += v.x; acc.y += v.y; acc.z += v.z; acc.w += v.w;
    }
    if (ii < e && half == 0) {
      float4 v = xp[(size_t)srcs[ii] * 32 + sub];
      acc.x += v.x; acc.y += v.y; acc.z += v.z; acc.w += v.w;
    }
  }
  acc.x += __shfl_xor(acc.x, 32);
  acc.y += __shfl_xor(acc.y, 32);
  acc.z += __shfl_xor(acc.z, 32);
  acc.w += __shfl_xor(acc.w, 32);
  if (half == 0) {
    float c = (float)(deg > 0 ? deg : 1);
    float inv = 1.f / c;
    float4 o = make_float4(acc.x * inv, acc.y * inv, acc.z * inv, acc.w * inv);
    ((float4*)mean)[(size_t)node * 32 + sub] = o;
  }
}

// ---------------- fused layer-2 aggregate: float4/lane, 4 edges per wave-load ----------------
__global__ void k_aggr_fused64(const float* __restrict__ zA, const int* __restrict__ rpA,
                               const int* __restrict__ srcsA, float* __restrict__ outA, int nA,
                               const float* __restrict__ zB, const int* __restrict__ rpB,
                               const int* __restrict__ srcsB, float* __restrict__ outB, int nB,
                               const float* __restrict__ bias, int blocksA) {
  int blk = blockIdx.x;
  const float* zlr;
  const int* rp;
  const int* srcs;
  float* out;
  int n, nb0;
  if (blk < blocksA) { zlr = zA; rp = rpA; srcs = srcsA; out = outA; n = nA; nb0 = blk * 4; }
  else { zlr = zB; rp = rpB; srcs = srcsB; out = outB; n = nB; nb0 = (blk - blocksA) * 4; }
  int lane = threadIdx.x & 63;
  int node = nb0 + (threadIdx.x >> 6);
  if (node >= n) return;
  int s = rp[node], e = rp[node + 1];
  int deg = e - s;
  int q = lane >> 4;
  int sub = lane & 15;
  const float4* zp = (const float4*)zlr;
  float4 acc = make_float4(0.f, 0.f, 0.f, 0.f);
  int sv = 0;
  if (s + lane < e) sv = srcs[s + lane];
  int lim = deg < 64 ? deg : 64;
  int i = 0;
  for (; i + 8 <= lim; i += 8) {
    int s0 = __shfl(sv, i + q);
    int s1 = __shfl(sv, i + 4 + q);
    float4 v0 = zp[(size_t)s0 * 32 + sub];
    float4 v1 = zp[(size_t)s1 * 32 + sub];
    acc.x += v0.x + v1.x;
    acc.y += v0.y + v1.y;
    acc.z += v0.z + v1.z;
    acc.w += v0.w + v1.w;
  }
  for (; i + 4 <= lim; i += 4) {
    int s0 = __shfl(sv, i + q);
    float4 v = zp[(size_t)s0 * 32 + sub];
    acc.x += v.x; acc.y += v.y; acc.z += v.z; acc.w += v.w;
  }
  {
    int rem = lim - i;
    int s0 = __shfl(sv, i + q);
    if (q < rem) {
      float4 v = zp[(size_t)s0 * 32 + sub];
      acc.x += v.x; acc.y += v.y; acc.z += v.z; acc.w += v.w;
    }
    i = lim;
  }
  if (deg > 64) {  // rare tail, direct loads, same grouping
    int ii = s + 64;
    for (; ii + 8 <= e; ii += 8) {
      int s0 = srcs[ii + q];
      int s1 = srcs[ii + 4 + q];
      float4 v0 = zp[(size_t)s0 * 32 + sub];
      float4 v1 = zp[(size_t)s1 * 32 + sub];
      acc.x += v0.x + v1.x;
      acc.y += v0.y + v1.y;
      acc.z += v0.z + v1.z;
      acc.w += v0.w + v1.w;
    }
    for (; ii + 4 <= e; ii += 4) {
      int s0 = srcs[ii + q];
      float4 v = zp[(size_t)s0 * 32 + sub];
      acc.x += v.x; acc.y += v.y; acc.z += v.z; acc.w += v.w;
    }
    int rem = e - ii;
    if (q < rem) {
      int s0 = srcs[ii + q];
      float4 v = zp[(size_t)s0 * 32 + sub];
      acc.x += v.x; acc.y += v.y; acc.z += v.z; acc.w += v.w;
    }
  }
  acc.x += __shfl_xor(acc.x, 16);
  acc.y += __shfl_xor(acc.y, 16);
  acc.z += __shfl_xor(acc.z, 16);
  acc.w += __shfl_xor(acc.w, 16);
  acc.x += __shfl_xor(acc.x, 32);
  acc.y += __shfl_xor(acc.y, 32);
  acc.z += __shfl_xor(acc.z, 32);
  acc.w += __shfl_xor(acc.w, 32);
  if (q == 0) {
    float c = (float)(deg > 0 ? deg : 1);
    float inv = 1.f / c;
    float4 mb = ((const float4*)bias)[sub];
    float4 rt = zp[(size_t)node * 32 + 16 + sub];
    float v0 = acc.x * inv + mb.x + rt.x;
    float v1 = acc.y * inv + mb.y + rt.y;
    float v2 = acc.z * inv + mb.z + rt.z;
    float v3 = acc.w * inv + mb.w + rt.w;
    float4 o;
    o.x = v0 > 0.f ? v0 : 0.f;
    o.y = v1 > 0.f ? v1 : 0.f;
    o.z = v2 > 0.f ? v2 : 0.f;
    o.w = v3 > 0.f ? v3 : 0.f;
    ((float4*)out)[(size_t)node * 16 + sub] = o;
  }
}

// ---------------- fused SAGE layer-1 GEMM + layer-2 dual linear ----------------
// GEMM1: h = relu(mean@w1l^T + b1l + x@w1r^T)   (h kept in registers, 8x8/thread)
// GEMM2: z = [h@w2l^T | h@w2r^T]                (h transposed into s_a per 32-K chunk)
// v5: back to v2's LDS layout (swizzled s_w, W via LDS — v4's global-W hit L2
// latency and regressed 2.5x) but re-partitioned: 128-thread blocks, TM=64,
// SAME per-thread 8x8 tile. LDS-reads-per-FMA identical to v2; blocks 394->786
// (3.07/CU vs 1.53) so when one block sits in a barrier/drain, other blocks'
// waves fill the CU (v2's ~35us exposed-latency gap at 1.5 blocks/CU).
// FMA order per output unchanged -> bitwise-identical result.
__global__ __launch_bounds__(128) void k_sage_lin(
    const float* __restrict__ xinA, const float* __restrict__ meanA,
    float* __restrict__ zA, int nA,
    const float* __restrict__ xinB, const float* __restrict__ meanB,
    float* __restrict__ zB, int nB,
    const float* __restrict__ w1l, const float* __restrict__ b1l,
    const float* __restrict__ w1r,
    const float* __restrict__ w2l, const float* __restrict__ w2r, int blocksA) {
  constexpr int TM = 64, TK = 32;
  constexpr int SA = TM + 4;    // 68
  constexpr int SWS = 196;      // 16 j-groups of 8 floats at stride 12 (+4 tail pad)
  __shared__ float s_a[TK][SA];
  __shared__ float s_w[TK][SWS];
  int blk = blockIdx.x;
  const float* xin;
  const float* mean;
  float* zlr;
  int n, m0;
  if (blk < blocksA) { xin = xinA; mean = meanA; zlr = zA; n = nA; m0 = blk * TM; }
  else { xin = xinB; mean = meanB; zlr = zB; n = nB; m0 = (blk - blocksA) * TM; }
  int t = threadIdx.x;          // 128
  int tx = t & 15, ty = t >> 4; // ty 0..7
  int sub = t >> 3;             // 0..15
  int kv = (t & 7) << 2;
  int wg = sub >> 3, wo = sub & 7;  // W staging swizzle pieces (wg 0..1)

  float acc[8][8];
#pragma unroll
  for (int i = 0; i < 8; i++)
#pragma unroll
    for (int j = 0; j < 8; j++) acc[i][j] = 0.f;
  float h[8][8];
  float4 ra[4], rw[8];

  // prologue: prefetch chunk 0 (mean / w1l, k0 = 0)
#pragma unroll
  for (int p = 0; p < 4; p++) {
    int node = m0 + p * 16 + sub;
    ra[p] = make_float4(0.f, 0.f, 0.f, 0.f);
    if (node < n) ra[p] = *(const float4*)&mean[(size_t)node * 128 + kv];
  }
#pragma unroll
  for (int p = 0; p < 8; p++)
    rw[p] = *(const float4*)&w1l[(size_t)(p * 16 + sub) * 128 + kv];

  for (int c = 0; c < 12; c++) {
    __syncthreads();  // previous chunk's LDS reads complete
    if (c < 8) {
#pragma unroll
      for (int p = 0; p < 4; p++) {
        int col = p * 16 + sub;
        s_a[kv + 0][col] = ra[p].x;
        s_a[kv + 1][col] = ra[p].y;
        s_a[kv + 2][col] = ra[p].z;
        s_a[kv + 3][col] = ra[p].w;
      }
    } else {
      // h transpose: this thread's h cols tx*8+j lie in [k0,k0+32) iff txk in [0,4)
      int txk = tx - (c - 8) * 4;
      if (txk >= 0 && txk < 4) {
#pragma unroll
        for (int i = 0; i < 8; i++)
#pragma unroll
          for (int j = 0; j < 8; j++) s_a[txk * 8 + j][ty * 8 + i] = h[i][j];
      }
    }
#pragma unroll
    for (int p = 0; p < 8; p++) {
      int col = (p * 2 + wg) * 12 + wo;  // swizzled column (same j->col map as v2)
      s_w[kv + 0][col] = rw[p].x;
      s_w[kv + 1][col] = rw[p].y;
      s_w[kv + 2][col] = rw[p].z;
      s_w[kv + 3][col] = rw[p].w;
    }
    // issue next chunk's global loads; latency hides under this chunk's compute
    int cn = c + 1;
    if (cn < 12) {
      int k0n = (cn & 3) * 32;
      if (cn < 8) {
        const float* A = (cn < 4) ? mean : xin;
        const float* W = (cn < 4) ? w1l : w1r;
#pragma unroll
        for (int p = 0; p < 4; p++) {
          int node = m0 + p * 16 + sub;
          ra[p] = make_float4(0.f, 0.f, 0.f, 0.f);
          if (node < n) ra[p] = *(const float4*)&A[(size_t)node * 128 + k0n + kv];
        }
#pragma unroll
        for (int p = 0; p < 8; p++)
          rw[p] = *(const float4*)&W[(size_t)(p * 16 + sub) * 128 + k0n + kv];
      } else {
#pragma unroll
        for (int p = 0; p < 8; p++) {
          int j = p * 16 + sub;
          const float* W = (j < 64) ? &w2l[(size_t)j * 128] : &w2r[(size_t)(j - 64) * 128];
          rw[p] = *(const float4*)&W[k0n + kv];
        }
      }
    }
    __syncthreads();
#pragma unroll 8
    for (int kk = 0; kk < TK; kk++) {
      float4 a0 = *(const float4*)&s_a[kk][ty * 8];
      float4 a1 = *(const float4*)&s_a[kk][ty * 8 + 4];
      float av[8] = {a0.x, a0.y, a0.z, a0.w, a1.x, a1.y, a1.z, a1.w};
      float4 w0 = *(const float4*)&s_w[kk][tx * 12];
      float4 w1 = *(const float4*)&s_w[kk][tx * 12 + 4];
      float wv[8] = {w0.x, w0.y, w0.z, w0.w, w1.x, w1.y, w1.z, w1.w};
#pragma unroll
      for (int i = 0; i < 8; i++)
#pragma unroll
        for (int j = 0; j < 8; j++) acc[i][j] = fmaf(av[i], wv[j], acc[i][j]);
    }
    if (c == 7) {
      // GEMM1 done: bias + relu -> h in registers; reset acc for GEMM2
      float bj[8];
#pragma unroll
      for (int j = 0; j < 8; j++) bj[j] = b1l[tx * 8 + j];
#pragma unroll
      for (int i = 0; i < 8; i++)
#pragma unroll
        for (int j = 0; j < 8; j++) {
          float v = acc[i][j] + bj[j];
          h[i][j] = v > 0.f ? v : 0.f;
          acc[i][j] = 0.f;
        }
    }
  }
  // ---- epilogue: write z (no bias/relu) ----
#pragma unroll
  for (int i = 0; i < 8; i++) {
    int node = m0 + ty * 8 + i;
    if (node < n) {
#pragma unroll
      for (int q = 0; q < 8; q += 4) {
        float4 o = make_float4(acc[i][q + 0], acc[i][q + 1], acc[i][q + 2], acc[i][q + 3]);
        *(float4*)&zlr[(size_t)node * 128 + tx * 8 + q] = o;
      }
    }
  }
}

// ---------------- fused score + per-chunk bitonic top-50 (16 chunks of 313) ----------------
__global__ void k_score_topk_local(const float* __restrict__ out1,
                                   const float* __restrict__ out2,
                                   ull* __restrict__ cand) {
  __shared__ ull s[512];
  __shared__ float brow[64];
  int blk = blockIdx.x;  // 0..159
  int b = blk >> 4, c = blk & 15;
  int t = threadIdx.x;   // 256
  if (t < 64) brow[t] = out2[198 * 64 + t];
  __syncthreads();
  const float4* b4 = (const float4*)brow;
  float b2 = 0.f;
#pragma unroll
  for (int q = 0; q < 16; q++) {
    float4 w = b4[q];
    b2 = fmaf(w.x, w.x, fmaf(w.y, w.y, fmaf(w.z, w.z, fmaf(w.w, w.w, b2))));
  }
#pragma unroll
  for (int p = 0; p < 2; p++) {
    int i = p * 256 + t;
    ull key = 0ULL;
    int gidx = c * CHSZ + i;
    if (i < CHSZ && gidx < NPG) {
      const float4* ap = (const float4*)&out1[((size_t)b * NPG + gidx) * 64];
      float dot = 0.f, a2 = 0.f;
#pragma unroll
      for (int q = 0; q < 16; q++) {
        float4 a = ap[q];
        float4 w = b4[q];
        dot = fmaf(a.x, w.x, fmaf(a.y, w.y, fmaf(a.z, w.z, fmaf(a.w, w.w, dot))));
        a2 = fmaf(a.x, a.x, fmaf(a.y, a.y, fmaf(a.z, a.z, fmaf(a.w, a.w, a2))));
      }
      float d2 = a2 + b2 - 2.f * dot;
      float sc = sqrtf(fmaxf(d2, 0.f));
      key = ((ull)__float_as_uint(sc) << 32) | (unsigned int)(~gidx);
    }
    s[i] = key;
  }
  __syncthreads();
  for (int k = 2; k <= 512; k <<= 1) {
    for (int j = k >> 1; j > 0; j >>= 1) {
#pragma unroll
      for (int p = 0; p < 2; p++) {
        int i = p * 256 + t;
        int l = i ^ j;
        if (l > i) {
          bool up = ((i & k) != 0);
          ull a = s[i], bb = s[l];
          if ((a > bb) == up) { s[i] = bb; s[l] = a; }
        }
      }
      __syncthreads();
    }
  }
  if (t < KSEL) cand[(b * CHUNKS + c) * KSEL + t] = s[t];
}

// ---------------- top-50 merge: sort 800 candidates (pad 1024), emit sel ----------------
__global__ void k_topk_merge(const ull* __restrict__ cand, int* __restrict__ sel) {
  __shared__ ull s[1024];
  int b = blockIdx.x, t = threadIdx.x;  // 256
#pragma unroll
  for (int p = 0; p < 4; p++) {
    int i = p * 256 + t;
    s[i] = (i < CHUNKS * KSEL) ? cand[b * CHUNKS * KSEL + i] : 0ULL;
  }
  __syncthreads();
  for (int k = 2; k <= 1024; k <<= 1) {
    for (int j = k >> 1; j > 0; j >>= 1) {
#pragma unroll
      for (int p = 0; p < 4; p++) {
        int i = p * 256 + t;
        int l = i ^ j;
        if (l > i) {
          bool up = ((i & k) != 0);
          ull a = s[i], bb = s[l];
          if ((a > bb) == up) { s[i] = bb; s[l] = a; }
        }
      }
      __syncthreads();
    }
  }
  if (t < KSEL) {
    int gidx = (int)(~((unsigned int)s[t]));
    sel[b * KSEL + t] = b * NPG + gidx;
  }
}

// ---------------- dist rows for selected nodes: D[500][199] ----------------
__global__ void k_dist_rows(const float* __restrict__ out1, const float* __restrict__ out2,
                            const int* __restrict__ sel, float* __restrict__ D) {
  __shared__ float arow[64];
  int i = blockIdx.x;   // 0..499
  int t = threadIdx.x;  // 256
  int node = sel[i];
  if (t < 64) arow[t] = out1[(size_t)node * 64 + t];
  __syncthreads();
  float a2 = 0.f;
#pragma unroll
  for (int f = 0; f < 64; f++) a2 = fmaf(arow[f], arow[f], a2);
  for (int nn = t; nn < N2; nn += 256) {
    float dot = 0.f, b2 = 0.f;
#pragma unroll 8
    for (int f = 0; f < 64; f++) {
      float bv = out2[nn * 64 + f];
      dot = fmaf(arow[f], bv, dot);
      b2 = fmaf(bv, bv, b2);
    }
    float d2 = a2 + b2 - 2.f * dot;
    D[i * N2 + nn] = sqrtf(fmaxf(d2, 0.f));
  }
}

// ---------------- fc1 dot: one block per output feature j, all 10 graphs ----------------
__global__ void k_fc1_dot(const float* __restrict__ D, const float* __restrict__ w,
                          float* __restrict__ h1pre) {
  constexpr int M = KSEL * N2;  // 9950
  constexpr int M2 = M / 2;     // 4975
  int j = blockIdx.x;           // 0..127
  int t = threadIdx.x;          // 256
  const float2* wp = (const float2*)(w + (size_t)j * M);
  float acc[Bg];
#pragma unroll
  for (int b = 0; b < Bg; b++) acc[b] = 0.f;
  for (int m = t; m < M2; m += 256) {
    float2 wv = wp[m];
#pragma unroll
    for (int b = 0; b < Bg; b++) {
      float2 dv = ((const float2*)(D + (size_t)b * M))[m];
      acc[b] = fmaf(dv.x, wv.x, fmaf(dv.y, wv.y, acc[b]));
    }
  }
  __shared__ float ws_[4][Bg];
  int lane = t & 63, wv_ = t >> 6;
#pragma unroll
  for (int b = 0; b < Bg; b++) {
    float v = acc[b];
    for (int off = 32; off; off >>= 1) v += __shfl_xor(v, off);
    if (lane == 0) ws_[wv_][b] = v;
  }
  __syncthreads();
  if (t < Bg) h1pre[t * 128 + j] = ws_[0][t] + ws_[1][t] + ws_[2][t] + ws_[3][t];
}

// ---------------- fused: fc1 bias+LN+relu, fc2+LN+relu, fc3+sigmoid ----------------
__global__ void k_fc123(const float* __restrict__ h1pre, const float* __restrict__ fc1b,
                        const float* __restrict__ g1, const float* __restrict__ be1,
                        const float* __restrict__ w2, const float* __restrict__ b2v,
                        const float* __restrict__ g2, const float* __restrict__ be2,
                        const float* __restrict__ w3, const float* __restrict__ b3,
                        float* __restrict__ out) {
  __shared__ float wsum[2];
  __shared__ float sh[128];
  int b = blockIdx.x, t = threadIdx.x;  // 128
  float acc = h1pre[b * 128 + t] + fc1b[t];
  int lane = t & 63, wv_ = t >> 6;
  float ssum = acc;
  for (int off = 32; off; off >>= 1) ssum += __shfl_xor(ssum, off);
  if (lane == 0) wsum[wv_] = ssum;
  __syncthreads();
  float mu = (wsum[0] + wsum[1]) / 128.f;
  __syncthreads();
  float d = acc - mu;
  float vv = d * d;
  for (int off = 32; off; off >>= 1) vv += __shfl_xor(vv, off);
  if (lane == 0) wsum[wv_] = vv;
  __syncthreads();
  float var = (wsum[0] + wsum[1]) / 128.f;
  float r = rsqrtf(var + LN_EPS);
  float h = d * r * g1[t] + be1[t];
  sh[t] = h > 0.f ? h : 0.f;
  __syncthreads();
  if (t < 64) {
    float a2 = b2v[t];
#pragma unroll 8
    for (int k = 0; k < 128; k++) a2 = fmaf(sh[k], w2[t * 128 + k], a2);
    float s2 = a2;
    for (int off = 32; off; off >>= 1) s2 += __shfl_xor(s2, off);
    float mu2 = s2 * (1.f / 64.f);
    float d2 = a2 - mu2;
    float vv2 = d2 * d2;
    for (int off = 32; off; off >>= 1) vv2 += __shfl_xor(vv2, off);
    float r2 = rsqrtf(vv2 * (1.f / 64.f) + LN_EPS);
    float h2 = d2 * r2 * g2[t] + be2[t];
    h2 = h2 > 0.f ? h2 : 0.f;
    float pp = h2 * w3[t];
    for (int off = 32; off; off >>= 1) pp += __shfl_xor(pp, off);
    if (t == 0) out[b] = 1.f / (1.f + expf(-(pp + b3[0])));
  }
}

extern "C" void kernel_launch(void* const* d_in, const int* in_sizes, int n_in,
                              void* d_out, int out_size, void* d_ws, size_t ws_size,
                              hipStream_t stream) {
  const float* x1 = (const float*)d_in[0];
  const int* ei1 = (const int*)d_in[1];
  const float* x2 = (const float*)d_in[3];
  const int* ei2 = (const int*)d_in[4];
  const float* w1l = (const float*)d_in[5];
  const float* b1l = (const float*)d_in[6];
  const float* w1r = (const float*)d_in[7];
  const float* w2l = (const float*)d_in[8];
  const float* b2l = (const float*)d_in[9];
  const float* w2r = (const float*)d_in[10];
  const float* fc1w = (const float*)d_in[11];
  const float* fc1b = (const float*)d_in[12];
  const float* ln1g = (const float*)d_in[13];
  const float* ln1b = (const float*)d_in[14];
  const float* fc2w = (const float*)d_in[15];
  const float* fc2b = (const float*)d_in[16];
  const float* ln2g = (const float*)d_in[17];
  const float* ln2b = (const float*)d_in[18];
  const float* fc3w = (const float*)d_in[19];
  const float* fc3b = (const float*)d_in[20];
  float* out = (float*)d_out;

  char* p = (char*)d_ws;
  auto alloc = [&](size_t bytes) {
    char* r = p;
    p += (bytes + 255) & ~(size_t)255;
    return r;
  };
  int* rp1 = (int*)alloc((N1 + 1) * 4);
  int* bcnt = (int*)alloc(NB * 4);
  unsigned int* bed = (unsigned int*)alloc((size_t)NB * BCAP * 4);
  int* srcs1 = (int*)alloc((size_t)E1 * 4);
  int* rp2 = (int*)alloc((N2 + 1) * 4);
  int* srcs2 = (int*)alloc(E2 * 4);
  float* bufMean = (float*)alloc((size_t)N1 * 128 * 4);  // mean agg (layer 1)
  float* bufZ = (float*)alloc((size_t)N1 * 128 * 4);     // zlr = [h@w2l^T | h@w2r^T]
  float* out1b = (float*)alloc((size_t)N1 * 64 * 4);
  float* mean2 = (float*)alloc((size_t)N2 * 128 * 4);
  float* z2g = (float*)alloc((size_t)N2 * 128 * 4);
  float* out2b = (float*)alloc((size_t)N2 * 64 * 4);
  int* sel = (int*)alloc(Bg * KSEL * 4);
  ull* cand = (ull*)alloc((size_t)Bg * CHUNKS * KSEL * 8);
  float* Dm = (float*)alloc((size_t)Bg * KSEL * N2 * 4);
  float* h1pre = (float*)alloc(Bg * 128 * 4);

  const int nEdgeBlocks = (E1 + EBT - 1) / EBT;
  const int aggrBlocksA = (N1 + 3) / 4;
  const int aggrBlocksB = (N2 + 3) / 4;
  const int gemmBlocksA = (N1 + 63) / 64;
  const int gemmBlocksB = (N2 + 63) / 64;

  // ---- CSR build ----
  hipMemsetAsync(bcnt, 0, NB * 4, stream);
  k_bucket<<<nEdgeBlocks + 1, 256, 0, stream>>>(ei1, bcnt, bed, ei2, rp2, srcs2);
  k_csr_bucket<<<NB, 1024, 0, stream>>>(bcnt, bed, rp1, srcs1);
  // ---- GNN (both graphs per launch) ----
  k_aggr128<<<aggrBlocksA + aggrBlocksB, 256, 0, stream>>>(
      x1, rp1, srcs1, bufMean, N1, x2, rp2, srcs2, mean2, N2, aggrBlocksA);
  k_sage_lin<<<gemmBlocksA + gemmBlocksB, 128, 0, stream>>>(
      x1, bufMean, bufZ, N1, x2, mean2, z2g, N2, w1l, b1l, w1r, w2l, w2r, gemmBlocksA);
  k_aggr_fused64<<<aggrBlocksA + aggrBlocksB, 256, 0, stream>>>(
      bufZ, rp1, srcs1, out1b, N1, z2g, rp2, srcs2, out2b, N2, b2l, aggrBlocksA);
  // ---- head ----
  k_score_topk_local<<<Bg * CHUNKS, 256, 0, stream>>>(out1b, out2b, cand);
  k_topk_merge<<<Bg, 256, 0, stream>>>(cand, sel);
  k_dist_rows<<<Bg * KSEL, 256, 0, stream>>>(out1b, out2b, sel, Dm);
  k_fc1_dot<<<128, 256, 0, stream>>>(Dm, fc1w, h1pre);
  k_fc123<<<Bg, 128, 0, stream>>>(h1pre, fc1b, ln1g, ln1b, fc2w, fc2b, ln2g, ln2b,
                                  fc3w, fc3b, out);
}